// Round 3
// baseline (413.295 us; speedup 1.0000x reference)
//
#include <hip/hip_runtime.h>

typedef unsigned short u16;
typedef __attribute__((ext_vector_type(8))) short s16x8;
typedef __attribute__((ext_vector_type(4))) short s16x4;
typedef __attribute__((ext_vector_type(4))) float f32x4;

__device__ __forceinline__ u16 f2bf(float f) {
    unsigned int u;
    __builtin_memcpy(&u, &f, 4);
    unsigned int r = u + 0x7FFFu + ((u >> 16) & 1u);   // RNE
    return (u16)(r >> 16);
}

// packed f32 pair -> bf16 pair (RNE), lo = cvt(a), hi = cvt(b)
__device__ __forceinline__ unsigned int cvt_pk_bf16(float a, float b) {
    unsigned int r;
    asm("v_cvt_pk_bf16_f32 %0, %1, %2" : "=v"(r) : "v"(a), "v"(b));
    return r;
}

__device__ __forceinline__ void gl_lds16(const u16* g, u16* l) {
    __builtin_amdgcn_global_load_lds(
        (const __attribute__((address_space(1))) unsigned int*)g,
        (__attribute__((address_space(3))) unsigned int*)l,
        16, 0, 0);
}

// ---------------------------------------------------------------------------
// Transpose f32 -> bf16: out[c][r] = bf16(in[r][c]). grid = (cols/64, rows/64)
// ---------------------------------------------------------------------------
__global__ __launch_bounds__(256) void k_transpose(const float* __restrict__ in,
                                                   u16* __restrict__ out,
                                                   int rows, int cols) {
    __shared__ float tile[64][65];
    int bx = blockIdx.x * 64, by = blockIdx.y * 64;
    int tx = threadIdx.x & 63, ty = threadIdx.x >> 6;
    for (int i = ty; i < 64; i += 4)
        tile[i][tx] = in[(size_t)(by + i) * cols + bx + tx];
    __syncthreads();
    for (int i = ty; i < 64; i += 4)
        out[(size_t)(bx + i) * rows + by + tx] = f2bf(tile[tx][i]);
}

// ---------------------------------------------------------------------------
// GEMM1 fused with pixel-unshuffle. Round-3: 256x256 tile, 8 waves (512 thr),
// split-K=4. Rationale: round-2 counters showed the kernel is L2/L3
// BANDWIDTH bound (~7.4 TB/s effective); 256^2 tiles halve bytes moved
// (A 805->402 MB, B 403->202 MB).
//   P[z][8192][768] = unshuffle(x)[:, z*1024:(z+1)*1024] @ WqkvT^T
// A staging: per K-step (one c0) the source is ONE CONTIGUOUS 64KB block
// of x. Thread reads 8 float4 (seg 0..7) at seg*2048 + tid*4 f32; mapping:
//   img row = seg*8 + wave  ->  row-in-tile = seg*32 + xx, k = wave*8+(t&1)*4
// cvt_pk -> ds_write_b64 into XOR-swizzled As (byte ^= (row&7)<<4), which is
// at the 4-cycle write floor and conflict-free on the b128 MFMA reads.
// B: global_load_lds width 16 into linear Bs.
// grid 384 (= 32 tmi x 3 tn x 4 z), XCD-chunked: z constant per XCD so each
// XCD's B working set (3 panels, 1.5 MB) is L2-resident.
// ---------------------------------------------------------------------------
__global__ __launch_bounds__(512, 1) void k_gemm_qkv(const float* __restrict__ x,
                                                     const u16* __restrict__ Bt,
                                                     float* __restrict__ P) {
    const int K = 4096;
    __shared__ u16 As[256 * 64];   // XOR-swizzled
    __shared__ u16 Bs[256 * 64];   // linear
    const int tid = threadIdx.x;
    const int wave = tid >> 6, lane = tid & 63;
    const int quad = lane >> 4, l15 = lane & 15;
    const int wm = wave >> 2, wn = wave & 3;   // wave tile: 128M x 64N

    // XCD-chunked bijective swizzle: 384 = 8 * 48. rem ordered so tn is
    // innermost (A-panel sharers adjacent) and z is outermost (per-XCD
    // B working set = 3 panels).
    int lin = blockIdx.x;
    int rem = (lin & 7) * 48 + (lin >> 3);
    int tn3 = rem % 3;
    int q   = rem / 3;          // 0..127
    int z   = q >> 5;           // 0..3
    int tmi = q & 31;           // 0..31
    const int tm = tmi * 256, tn = tn3 * 256;

    // ---- A-staging geometry ----
    const int b   = tm >> 10;
    const int yy0 = (tm & 1023) >> 5;          // multiple of 8
    const float* asrc = x + ((size_t)(b * 64 + z * 16)) * 65536
                          + yy0 * 2048 + tid * 4;

    // LDS write dst (fixed per thread, per seg)
    u16* dstA[8];
#pragma unroll
    for (int seg = 0; seg < 8; ++seg) {
        int xx  = (tid >> 1) & 31;
        int row = seg * 32 + xx;
        int k2  = wave * 16 + (tid & 1) * 8;          // k*2 bytes
        int byteoff = (row * 128 + k2) ^ ((row & 7) << 4);
        dstA[seg] = (u16*)((char*)As + byteoff);
    }

    // prologue: prefetch iter 0
    float4 va[8];
#pragma unroll
    for (int seg = 0; seg < 8; ++seg)
        va[seg] = *(const float4*)(asrc + seg * 2048);

    f32x4 acc[8][4] = {};

    for (int it = 0; it < 16; ++it) {
        int k0 = z * 1024 + it * 64;
        __syncthreads();
        // B tile: async global->LDS, width 16. 2048 16B-chunks, 4/thread.
#pragma unroll
        for (int qq = 0; qq < 4; ++qq) {
            int chunk = qq * 512 + tid;
            int row = chunk >> 3, kc = chunk & 7;
            gl_lds16(Bt + (size_t)(tn + row) * K + k0 + kc * 8,
                     Bs + chunk * 8);
        }
        // A tile: cvt 4 f32 -> uint2, swizzled ds_write_b64 per seg
#pragma unroll
        for (int seg = 0; seg < 8; ++seg) {
            uint2 pk;
            pk.x = cvt_pk_bf16(va[seg].x, va[seg].y);
            pk.y = cvt_pk_bf16(va[seg].z, va[seg].w);
            *(uint2*)dstA[seg] = pk;
        }
        __syncthreads();
        // prefetch next iter's A during the MFMA phase
        if (it < 15) {
            asrc += 65536;
#pragma unroll
            for (int seg = 0; seg < 8; ++seg)
                va[seg] = *(const float4*)(asrc + seg * 2048);
        }
        // MFMA: wave computes 128x64 (8 M-frags x 4 N-frags)
        for (int kk = 0; kk < 64; kk += 32) {
            s16x8 af[8], bf[4];
#pragma unroll
            for (int i = 0; i < 8; ++i) {
                int row = wm * 128 + i * 16 + l15;
                int byteoff = (row * 128 + kk * 2 + quad * 16) ^ ((l15 & 7) << 4);
                af[i] = *(const s16x8*)((const char*)As + byteoff);
            }
#pragma unroll
            for (int j = 0; j < 4; ++j)
                bf[j] = *(const s16x8*)(Bs + (wn * 64 + j * 16 + l15) * 64 + kk + quad * 8);
#pragma unroll
            for (int i = 0; i < 8; ++i)
#pragma unroll
                for (int j = 0; j < 4; ++j)
                    acc[i][j] = __builtin_amdgcn_mfma_f32_16x16x32_bf16(af[i], bf[j], acc[i][j], 0, 0, 0);
        }
    }

    float* Pz = P + (size_t)z * 8192 * 768;
    for (int i = 0; i < 8; ++i) {
        int mb = tm + wm * 128 + i * 16 + quad * 4;
        for (int j = 0; j < 4; ++j) {
            int col = tn + wn * 64 + j * 16 + l15;
            for (int r = 0; r < 4; ++r)
                Pz[(size_t)(mb + r) * 768 + col] = acc[i][j][r];
        }
    }
}

// ---------------------------------------------------------------------------
// Split-K(4) reduce + scatter. Q,K -> [bh][n][d]; V -> TRANSPOSED Vt[bh][d][n]
// grid (12, 128), block 256.
// ---------------------------------------------------------------------------
__global__ __launch_bounds__(256) void k_qkv_reduce(const float* __restrict__ P,
                                                    u16* __restrict__ Qo,
                                                    u16* __restrict__ Ko,
                                                    u16* __restrict__ Vt) {
    __shared__ u16 tile[64][65];
    const int tid = threadIdx.x;
    const int ct = blockIdx.x, mt = blockIdx.y;
    const int c_l = tid & 63;
    const int col = ct * 64 + c_l;
    const int mbase = mt * 64;
    const size_t NP = (size_t)8192 * 768;
    const float* P1 = P + NP;
    const float* P2 = P + 2 * NP;
    const float* P3 = P + 3 * NP;

    if (ct < 8) {                       // Q (ct<4) / K (ct>=4), direct store
        int which = col >> 8;
        int h = (col >> 6) & 3, d = col & 63;
        u16* dst = (which == 0) ? Qo : Ko;
        for (int k = 0; k < 16; ++k) {
            int m = mbase + (tid >> 6) + k * 4;
            size_t off = (size_t)m * 768 + col;
            float v = P[off] + P1[off] + P2[off] + P3[off];
            int b = m >> 10, n = m & 1023;
            dst[((size_t)((b * 4 + h) * 1024 + n)) * 64 + d] = f2bf(v);
        }
    } else {                            // V: transpose to Vt[bh][d][n]
        int h = ct - 8;
        int b = mbase >> 10;
        int nbase = mbase & 1023;
        for (int k = 0; k < 16; ++k) {
            int ml = (tid >> 6) + k * 4;
            int m = mbase + ml;
            size_t off = (size_t)m * 768 + col;
            float v = P[off] + P1[off] + P2[off] + P3[off];
            tile[ml][c_l] = f2bf(v);
        }
        __syncthreads();
        for (int k = 0; k < 16; ++k) {
            int d = (tid >> 6) + k * 4;
            Vt[((size_t)((b * 4 + h) * 64 + d)) * 1024 + nbase + c_l] = tile[c_l][d];
        }
    }
}

// ---------------------------------------------------------------------------
// Flash attention. K tile: flat 8KB contiguous -> global_load_lds width16.
// V pre-transposed in global (Vt[bh][d][n]) -> vector load + ds_write_b128
// into padded Vts[64][68]. grid (16, 32), block 256.
// ---------------------------------------------------------------------------
__global__ __launch_bounds__(256) void k_attn(const u16* __restrict__ Qb,
                                              const u16* __restrict__ Kb,
                                              const u16* __restrict__ Vt,
                                              u16* __restrict__ aout) {
    const int bh = blockIdx.y;
    const int q0 = blockIdx.x * 64;
    const int tid = threadIdx.x;
    const int wave = tid >> 6, lane = tid & 63;
    const int quad = lane >> 4, l15 = lane & 15;
    const size_t base = (size_t)bh * 1024 * 64;
    const float scale = 0.125f;

    __shared__ u16 Ks[64 * 64];
    __shared__ u16 Vts[64 * 68];     // [d][kv], pad 68
    __shared__ u16 Ps[4][16 * 64];   // per-wave P scratch

    s16x8 aq0, aq1;
    {
        const u16* qp = Qb + base + (size_t)(q0 + wave * 16 + l15) * 64 + quad * 8;
        aq0 = *(const s16x8*)(qp);
        aq1 = *(const s16x8*)(qp + 32);
    }

    float m_i[4], l_i[4];
    f32x4 o[4] = {};
    for (int r = 0; r < 4; ++r) { m_i[r] = -1e30f; l_i[r] = 0.f; }

    const int vrow = tid >> 2, vpart = tid & 3;

    for (int t = 0; t < 16; ++t) {
        __syncthreads();
        // K tile: 4096 contiguous u16 -> LDS, async 16B per lane
        for (int e = 0; e < 2; ++e) {
            int s = e * 256 + tid;
            gl_lds16(Kb + base + (size_t)t * 4096 + s * 8, Ks + s * 8);
        }
        // V tile from Vt: row vrow, 16 u16 per thread, ds_write_b128 x2
        {
            const u16* src = Vt + base + (size_t)vrow * 1024 + t * 64 + vpart * 16;
            s16x8 a = *(const s16x8*)(src);
            s16x8 b2 = *(const s16x8*)(src + 8);
            *(s16x8*)(Vts + vrow * 68 + vpart * 16) = a;
            *(s16x8*)(Vts + vrow * 68 + vpart * 16 + 8) = b2;
        }
        __syncthreads();

        // S = Q K^T (wave: 16 q-rows x 64 kv-cols)
        f32x4 s4[4];
        for (int j = 0; j < 4; ++j) {
            const u16* kr = Ks + (j * 16 + l15) * 64 + quad * 8;
            s16x8 b0 = *(const s16x8*)(kr);
            s16x8 b1 = *(const s16x8*)(kr + 32);
            f32x4 c = {};
            c = __builtin_amdgcn_mfma_f32_16x16x32_bf16(aq0, b0, c, 0, 0, 0);
            c = __builtin_amdgcn_mfma_f32_16x16x32_bf16(aq1, b1, c, 0, 0, 0);
            s4[j] = c;
        }

        // online softmax; lane's rows are quad*4 + r
        for (int r = 0; r < 4; ++r) {
            float sv0 = s4[0][r] * scale, sv1 = s4[1][r] * scale;
            float sv2 = s4[2][r] * scale, sv3 = s4[3][r] * scale;
            float mt = fmaxf(fmaxf(sv0, sv1), fmaxf(sv2, sv3));
            for (int off = 1; off < 16; off <<= 1)
                mt = fmaxf(mt, __shfl_xor(mt, off, 64));
            float mn = fmaxf(m_i[r], mt);
            float alpha = __expf(m_i[r] - mn);
            m_i[r] = mn;
            float p0 = __expf(sv0 - mn), p1 = __expf(sv1 - mn);
            float p2 = __expf(sv2 - mn), p3 = __expf(sv3 - mn);
            u16* pw = Ps[wave] + (quad * 4 + r) * 64 + l15;
            pw[0]  = f2bf(p0);
            pw[16] = f2bf(p1);
            pw[32] = f2bf(p2);
            pw[48] = f2bf(p3);
            float rs = p0 + p1 + p2 + p3;
            for (int off = 1; off < 16; off <<= 1)
                rs += __shfl_xor(rs, off, 64);
            l_i[r] = l_i[r] * alpha + rs;
            for (int dt = 0; dt < 4; ++dt) o[dt][r] *= alpha;
        }

        // O += P @ V
        for (int kk = 0; kk < 64; kk += 32) {
            s16x8 pf = *(const s16x8*)(Ps[wave] + l15 * 64 + kk + quad * 8);
            for (int dt = 0; dt < 4; ++dt) {
                const u16* vr = Vts + (dt * 16 + l15) * 68 + kk + quad * 8;
                s16x4 v0 = *(const s16x4*)(vr);
                s16x4 v1 = *(const s16x4*)(vr + 4);
                s16x8 vf;
                vf[0] = v0[0]; vf[1] = v0[1]; vf[2] = v0[2]; vf[3] = v0[3];
                vf[4] = v1[0]; vf[5] = v1[1]; vf[6] = v1[2]; vf[7] = v1[3];
                o[dt] = __builtin_amdgcn_mfma_f32_16x16x32_bf16(pf, vf, o[dt], 0, 0, 0);
            }
        }
    }

    int b = bh >> 2, h = bh & 3;
    float rl[4];
    for (int r = 0; r < 4; ++r) rl[r] = 1.0f / l_i[r];
    for (int dt = 0; dt < 4; ++dt)
        for (int r = 0; r < 4; ++r) {
            int qrow = q0 + wave * 16 + quad * 4 + r;
            aout[((size_t)(b) * 1024 + qrow) * 256 + h * 64 + dt * 16 + l15] =
                f2bf(o[dt][r] * rl[r]);
        }
}

// ---------------------------------------------------------------------------
// GEMM2: y[8192][4096] = aout[8192][256] @ W_outT^T + bias, fused shuffle.
// ---------------------------------------------------------------------------
__global__ __launch_bounds__(256) void k_gemm_out(const u16* __restrict__ A,
                                                  const u16* __restrict__ Bt,
                                                  const float* __restrict__ bias,
                                                  float* __restrict__ out) {
    const int K = 256;
    __shared__ u16 As[128 * 64];
    __shared__ u16 Bs[128 * 64];
    const int tid = threadIdx.x;
    const int wave = tid >> 6, lane = tid & 63;
    const int quad = lane >> 4, l15 = lane & 15;
    const int wm = wave >> 1, wn = wave & 1;
    const int tm = blockIdx.y * 128, tn = blockIdx.x * 128;

    f32x4 acc[4][4] = {};

    for (int k0 = 0; k0 < K; k0 += 64) {
        __syncthreads();
        for (int t = 0; t < 4; ++t) {
            int c = wave * 256 + t * 64 + lane;
            int row = c >> 3, kc = c & 7;
            gl_lds16(A + (size_t)(tm + row) * K + k0 + kc * 8,
                     As + (wave * 256 + t * 64) * 8);
        }
        for (int t = 0; t < 4; ++t) {
            int c = wave * 256 + t * 64 + lane;
            int row = c >> 3, kc = c & 7;
            gl_lds16(Bt + (size_t)(tn + row) * K + k0 + kc * 8,
                     Bs + (wave * 256 + t * 64) * 8);
        }
        __syncthreads();
        for (int kk = 0; kk < 64; kk += 32) {
            s16x8 af[4], bf[4];
            for (int i = 0; i < 4; ++i)
                af[i] = *(const s16x8*)(As + (wm * 64 + i * 16 + l15) * 64 + kk + quad * 8);
            for (int j = 0; j < 4; ++j)
                bf[j] = *(const s16x8*)(Bs + (wn * 64 + j * 16 + l15) * 64 + kk + quad * 8);
            for (int i = 0; i < 4; ++i)
                for (int j = 0; j < 4; ++j)
                    acc[i][j] = __builtin_amdgcn_mfma_f32_16x16x32_bf16(af[i], bf[j], acc[i][j], 0, 0, 0);
        }
    }

    for (int i = 0; i < 4; ++i) {
        int mb = tm + wm * 64 + i * 16 + quad * 4;
        for (int j = 0; j < 4; ++j) {
            int col = tn + wn * 64 + j * 16 + l15;
            float bb = bias[col];
            int c0 = col >> 6, r1 = (col >> 3) & 7, r2 = col & 7;
            for (int r = 0; r < 4; ++r) {
                int m = mb + r;
                int b = m >> 10, n = m & 1023, yy = n >> 5, xx = n & 31;
                size_t oidx = ((size_t)((b * 64 + c0) * 256 + yy * 8 + r1)) * 256 + xx * 8 + r2;
                out[oidx] = acc[i][j][r] + bb;
            }
        }
    }
}

// ---------------------------------------------------------------------------
extern "C" void kernel_launch(void* const* d_in, const int* in_sizes, int n_in,
                              void* d_out, int out_size, void* d_ws, size_t ws_size,
                              hipStream_t stream) {
    (void)in_sizes; (void)n_in; (void)out_size; (void)ws_size;
    const float* x    = (const float*)d_in[0];
    const float* Wqkv = (const float*)d_in[1];   // [4096][768]
    const float* Wout = (const float*)d_in[2];   // [256][4096]
    const float* bout = (const float*)d_in[3];   // [4096]
    float* out = (float*)d_out;

    u16* ws     = (u16*)d_ws;
    u16* wqkvT  = ws;                        // 768*4096
    u16* woutT  = wqkvT + 3145728;           // 4096*256
    u16* Qb     = woutT + 1048576;           // 32*1024*64
    u16* Kb     = Qb + 2097152;
    u16* Vtb    = Kb + 2097152;              // V transposed [bh][d][n]
    u16* aoutb  = Vtb + 2097152;             // 8192*256
    float* Pp   = (float*)(aoutb + 2097152); // 4*8192*768 f32

    k_transpose<<<dim3(12, 64), 256, 0, stream>>>(Wqkv, wqkvT, 4096, 768);
    k_transpose<<<dim3(64, 4), 256, 0, stream>>>(Wout, woutT, 256, 4096);
    k_gemm_qkv<<<dim3(384, 1, 1), 512, 0, stream>>>(x, wqkvT, Pp);
    k_qkv_reduce<<<dim3(12, 128), 256, 0, stream>>>(Pp, Qb, Kb, Vtb);
    k_attn<<<dim3(16, 32), 256, 0, stream>>>(Qb, Kb, Vtb, aoutb);
    k_gemm_out<<<dim3(32, 64), 256, 0, stream>>>(aoutb, woutT, bout, out);
}

// Round 4
// 397.198 us; speedup vs baseline: 1.0405x; 1.0405x over previous
//
#include <hip/hip_runtime.h>

typedef unsigned short u16;
typedef __attribute__((ext_vector_type(8))) short s16x8;
typedef __attribute__((ext_vector_type(4))) short s16x4;
typedef __attribute__((ext_vector_type(4))) float f32x4;

__device__ __forceinline__ u16 f2bf(float f) {
    unsigned int u;
    __builtin_memcpy(&u, &f, 4);
    unsigned int r = u + 0x7FFFu + ((u >> 16) & 1u);   // RNE
    return (u16)(r >> 16);
}

// packed f32 pair -> bf16 pair (RNE), lo = cvt(a), hi = cvt(b)
__device__ __forceinline__ unsigned int cvt_pk_bf16(float a, float b) {
    unsigned int r;
    asm("v_cvt_pk_bf16_f32 %0, %1, %2" : "=v"(r) : "v"(a), "v"(b));
    return r;
}

__device__ __forceinline__ void gl_lds16(const u16* g, u16* l) {
    __builtin_amdgcn_global_load_lds(
        (const __attribute__((address_space(1))) unsigned int*)g,
        (__attribute__((address_space(3))) unsigned int*)l,
        16, 0, 0);
}

// ---------------------------------------------------------------------------
// Transpose f32 -> bf16: out[c][r] = bf16(in[r][c]). grid = (cols/64, rows/64)
// swz!=0: store k-index XOR'd by (((n>>1)&3)<<3) (u16 units) so that
// global_load_lds in k_gemm_qkv lands content-swizzled in LDS (rule:
// swizzle source + read, keep LDS-dest linear).
// ---------------------------------------------------------------------------
__global__ __launch_bounds__(256) void k_transpose(const float* __restrict__ in,
                                                   u16* __restrict__ out,
                                                   int rows, int cols, int swz) {
    __shared__ float tile[64][65];
    int bx = blockIdx.x * 64, by = blockIdx.y * 64;
    int tx = threadIdx.x & 63, ty = threadIdx.x >> 6;
    for (int i = ty; i < 64; i += 4)
        tile[i][tx] = in[(size_t)(by + i) * cols + bx + tx];
    __syncthreads();
    for (int i = ty; i < 64; i += 4) {
        int n = bx + i, k = by + tx;
        int ks = swz ? (k ^ (((n >> 1) & 3) << 3)) : k;
        out[(size_t)n * rows + ks] = f2bf(tile[tx][i]);
    }
}

// ---------------------------------------------------------------------------
// GEMM1 fused with pixel-unshuffle. Round-4: 256x256 tile, BK=32,
// DOUBLE-BUFFERED 2-phase async schedule (stage t+1 BEFORE MFMA on t, one
// barrier/iter) -- round-3 counters showed 79% stall from the fully-drained
// 2-barrier loop at 1 block/CU.
//   P[z][8192][768] = unshuffle(x)[:, z*1024:+1024] @ WqkvT^T
// A: reg-staged from x (coalesced 16 f32/thread), cvt_pk -> 2 ds_write_b128
//    into slot-swizzled As (byte ^= ((row>>1)&3)<<4; 8 rows -> 8 slots).
// B: global_load_lds from PRE-SWIZZLED wqkvT (same involution on read).
// grid 384 (32 tmi x 3 tn x 4 z), XCD-chunked, block 512 (8 waves 2Mx4N).
// ---------------------------------------------------------------------------
__global__ __launch_bounds__(512, 1) void k_gemm_qkv(const float* __restrict__ x,
                                                     const u16* __restrict__ Bt,
                                                     float* __restrict__ P) {
    __shared__ u16 As[2][256 * 32];
    __shared__ u16 Bs[2][256 * 32];
    const int tid = threadIdx.x;
    const int wave = tid >> 6, lane = tid & 63;
    const int quad = lane >> 4, l15 = lane & 15;
    const int wm = wave >> 2, wn = wave & 3;   // wave tile: 128M x 64N

    // XCD-chunked bijective swizzle: 384 = 8 * 48, tn innermost, z outermost.
    int lin = blockIdx.x;
    int rem = (lin & 7) * 48 + (lin >> 3);
    int tn3 = rem % 3;
    int q2  = rem / 3;          // 0..127
    int z   = q2 >> 5;          // 0..3
    int tmi = q2 & 31;          // 0..31
    const int tm = tmi * 256, tn = tn3 * 256;

    const int b   = tm >> 10;
    const int yy0 = (tm & 1023) >> 5;          // multiple of 8

    // ---- A-staging thread geometry (16 f32 = 2 tokens x 8 k) ----
    const int rr    = tid >> 4;      // 0..31
    const int col16 = tid & 15;
    const int yy_l  = rr >> 2, r1_l = rr & 3;
    const int m0    = yy_l * 32 + col16 * 2;   // first of 2 token rows

    u16* dstA0[2]; u16* dstA1[2];
#pragma unroll
    for (int bb = 0; bb < 2; ++bb) {
        int off0 = (m0 * 64 + r1_l * 16) ^ (((m0 >> 1) & 3) << 4);
        int off1 = ((m0 + 1) * 64 + r1_l * 16) ^ ((((m0 + 1) >> 1) & 3) << 4);
        dstA0[bb] = (u16*)((char*)As[bb] + off0);
        dstA1[bb] = (u16*)((char*)As[bb] + off1);
    }
    const float* planeBase = x + ((size_t)(b * 64)) * 65536
                               + ((yy0 + yy_l) * 8 + r1_l) * 256 + col16 * 16;
    // per it: c0 = z*16 + (it>>1), h2 = it&1 -> +c0*65536 + h2*4*256

    // B-staging: 2 gl_lds chunks/thread; source rows tn+(tid>>2) and +128.
    const int brow = tid >> 2, bo = (tid & 3) * 16;   // byte offset in 64B row
    const char* btb = (const char*)Bt;

    f32x4 acc[8][4] = {};
    float4 va[4];

    // ---- prologue: load+stage tile 0, prefetch va for tile 1 ----
    {
        const float* s = planeBase;           // it=0: c0=z*16, h2=0
        s += (size_t)(z * 16) * 65536;
#pragma unroll
        for (int j = 0; j < 4; ++j) va[j] = ((const float4*)s)[j];
    }
    {
        size_t koff = (size_t)z * 2048;       // bytes, it=0
        gl_lds16((const u16*)(btb + (size_t)(tn + brow) * 8192 + koff + bo),
                 Bs[0] + tid * 8);
        gl_lds16((const u16*)(btb + (size_t)(tn + 128 + brow) * 8192 + koff + bo),
                 Bs[0] + 4096 + tid * 8);
    }
    {
        uint4 pk0, pk1;
        pk0.x = cvt_pk_bf16(va[0].x, va[0].y); pk0.y = cvt_pk_bf16(va[0].z, va[0].w);
        pk0.z = cvt_pk_bf16(va[1].x, va[1].y); pk0.w = cvt_pk_bf16(va[1].z, va[1].w);
        pk1.x = cvt_pk_bf16(va[2].x, va[2].y); pk1.y = cvt_pk_bf16(va[2].z, va[2].w);
        pk1.z = cvt_pk_bf16(va[3].x, va[3].y); pk1.w = cvt_pk_bf16(va[3].z, va[3].w);
        *(uint4*)dstA0[0] = pk0;
        *(uint4*)dstA1[0] = pk1;
    }
    {   // va <- tile 1 (c0 = z*16, h2 = 1)
        const float* s = planeBase + (size_t)(z * 16) * 65536 + 1024;
#pragma unroll
        for (int j = 0; j < 4; ++j) va[j] = ((const float4*)s)[j];
    }
    __syncthreads();

    int cur = 0;
    for (int it = 0; it < 32; ++it) {
        // ---- stage tile it+1 into buf cur^1 (issued BEFORE compute) ----
        if (it < 31) {
            int it1 = it + 1;
            size_t koff = (size_t)z * 2048 + (size_t)it1 * 64;
            gl_lds16((const u16*)(btb + (size_t)(tn + brow) * 8192 + koff + bo),
                     Bs[cur ^ 1] + tid * 8);
            gl_lds16((const u16*)(btb + (size_t)(tn + 128 + brow) * 8192 + koff + bo),
                     Bs[cur ^ 1] + 4096 + tid * 8);
            uint4 pk0, pk1;
            pk0.x = cvt_pk_bf16(va[0].x, va[0].y); pk0.y = cvt_pk_bf16(va[0].z, va[0].w);
            pk0.z = cvt_pk_bf16(va[1].x, va[1].y); pk0.w = cvt_pk_bf16(va[1].z, va[1].w);
            pk1.x = cvt_pk_bf16(va[2].x, va[2].y); pk1.y = cvt_pk_bf16(va[2].z, va[2].w);
            pk1.z = cvt_pk_bf16(va[3].x, va[3].y); pk1.w = cvt_pk_bf16(va[3].z, va[3].w);
            *(uint4*)dstA0[cur ^ 1] = pk0;
            *(uint4*)dstA1[cur ^ 1] = pk1;
        }
        // ---- prefetch va for tile it+2 ----
        if (it < 30) {
            int it2 = it + 2;
            const float* s = planeBase + (size_t)(z * 16 + (it2 >> 1)) * 65536
                           + (it2 & 1) * 1024;
#pragma unroll
            for (int j = 0; j < 4; ++j) va[j] = ((const float4*)s)[j];
        }
        // ---- compute on buf cur ----
        s16x8 af[8], bf[4];
#pragma unroll
        for (int i = 0; i < 8; ++i) {
            int row = wm * 128 + i * 16 + l15;
            int off = (row * 64 + quad * 16) ^ (((row >> 1) & 3) << 4);
            af[i] = *(const s16x8*)((const char*)As[cur] + off);
        }
#pragma unroll
        for (int j = 0; j < 4; ++j) {
            int row = wn * 64 + j * 16 + l15;
            int off = (row * 64 + quad * 16) ^ (((row >> 1) & 3) << 4);
            bf[j] = *(const s16x8*)((const char*)Bs[cur] + off);
        }
        __builtin_amdgcn_s_setprio(1);
#pragma unroll
        for (int i = 0; i < 8; ++i)
#pragma unroll
            for (int j = 0; j < 4; ++j)
                acc[i][j] = __builtin_amdgcn_mfma_f32_16x16x32_bf16(af[i], bf[j], acc[i][j], 0, 0, 0);
        __builtin_amdgcn_s_setprio(0);
        __syncthreads();
        cur ^= 1;
    }

    float* Pz = P + (size_t)z * 8192 * 768;
    for (int i = 0; i < 8; ++i) {
        int mb = tm + wm * 128 + i * 16 + quad * 4;
        for (int j = 0; j < 4; ++j) {
            int col = tn + wn * 64 + j * 16 + l15;
            for (int r = 0; r < 4; ++r)
                Pz[(size_t)(mb + r) * 768 + col] = acc[i][j][r];
        }
    }
}

// ---------------------------------------------------------------------------
// Split-K(4) reduce + scatter. Q,K -> [bh][n][d]; V -> TRANSPOSED Vt[bh][d][n]
// grid (12, 128), block 256.
// ---------------------------------------------------------------------------
__global__ __launch_bounds__(256) void k_qkv_reduce(const float* __restrict__ P,
                                                    u16* __restrict__ Qo,
                                                    u16* __restrict__ Ko,
                                                    u16* __restrict__ Vt) {
    __shared__ u16 tile[64][65];
    const int tid = threadIdx.x;
    const int ct = blockIdx.x, mt = blockIdx.y;
    const int c_l = tid & 63;
    const int col = ct * 64 + c_l;
    const int mbase = mt * 64;
    const size_t NP = (size_t)8192 * 768;
    const float* P1 = P + NP;
    const float* P2 = P + 2 * NP;
    const float* P3 = P + 3 * NP;

    if (ct < 8) {                       // Q (ct<4) / K (ct>=4), direct store
        int which = col >> 8;
        int h = (col >> 6) & 3, d = col & 63;
        u16* dst = (which == 0) ? Qo : Ko;
        for (int k = 0; k < 16; ++k) {
            int m = mbase + (tid >> 6) + k * 4;
            size_t off = (size_t)m * 768 + col;
            float v = P[off] + P1[off] + P2[off] + P3[off];
            int b = m >> 10, n = m & 1023;
            dst[((size_t)((b * 4 + h) * 1024 + n)) * 64 + d] = f2bf(v);
        }
    } else {                            // V: transpose to Vt[bh][d][n]
        int h = ct - 8;
        int b = mbase >> 10;
        int nbase = mbase & 1023;
        for (int k = 0; k < 16; ++k) {
            int ml = (tid >> 6) + k * 4;
            int m = mbase + ml;
            size_t off = (size_t)m * 768 + col;
            float v = P[off] + P1[off] + P2[off] + P3[off];
            tile[ml][c_l] = f2bf(v);
        }
        __syncthreads();
        for (int k = 0; k < 16; ++k) {
            int d = (tid >> 6) + k * 4;
            Vt[((size_t)((b * 4 + h) * 64 + d)) * 1024 + nbase + c_l] = tile[c_l][d];
        }
    }
}

// ---------------------------------------------------------------------------
// Flash attention. K tile: flat 8KB contiguous -> global_load_lds width16.
// V pre-transposed in global (Vt[bh][d][n]) -> vector load + ds_write_b128
// into padded Vts[64][68]. grid (16, 32), block 256.
// ---------------------------------------------------------------------------
__global__ __launch_bounds__(256) void k_attn(const u16* __restrict__ Qb,
                                              const u16* __restrict__ Kb,
                                              const u16* __restrict__ Vt,
                                              u16* __restrict__ aout) {
    const int bh = blockIdx.y;
    const int q0 = blockIdx.x * 64;
    const int tid = threadIdx.x;
    const int wave = tid >> 6, lane = tid & 63;
    const int quad = lane >> 4, l15 = lane & 15;
    const size_t base = (size_t)bh * 1024 * 64;
    const float scale = 0.125f;

    __shared__ u16 Ks[64 * 64];
    __shared__ u16 Vts[64 * 68];     // [d][kv], pad 68
    __shared__ u16 Ps[4][16 * 64];   // per-wave P scratch

    s16x8 aq0, aq1;
    {
        const u16* qp = Qb + base + (size_t)(q0 + wave * 16 + l15) * 64 + quad * 8;
        aq0 = *(const s16x8*)(qp);
        aq1 = *(const s16x8*)(qp + 32);
    }

    float m_i[4], l_i[4];
    f32x4 o[4] = {};
    for (int r = 0; r < 4; ++r) { m_i[r] = -1e30f; l_i[r] = 0.f; }

    const int vrow = tid >> 2, vpart = tid & 3;

    for (int t = 0; t < 16; ++t) {
        __syncthreads();
        // K tile: 4096 contiguous u16 -> LDS, async 16B per lane
        for (int e = 0; e < 2; ++e) {
            int s = e * 256 + tid;
            gl_lds16(Kb + base + (size_t)t * 4096 + s * 8, Ks + s * 8);
        }
        // V tile from Vt: row vrow, 16 u16 per thread, ds_write_b128 x2
        {
            const u16* src = Vt + base + (size_t)vrow * 1024 + t * 64 + vpart * 16;
            s16x8 a = *(const s16x8*)(src);
            s16x8 b2 = *(const s16x8*)(src + 8);
            *(s16x8*)(Vts + vrow * 68 + vpart * 16) = a;
            *(s16x8*)(Vts + vrow * 68 + vpart * 16 + 8) = b2;
        }
        __syncthreads();

        // S = Q K^T (wave: 16 q-rows x 64 kv-cols)
        f32x4 s4[4];
        for (int j = 0; j < 4; ++j) {
            const u16* kr = Ks + (j * 16 + l15) * 64 + quad * 8;
            s16x8 b0 = *(const s16x8*)(kr);
            s16x8 b1 = *(const s16x8*)(kr + 32);
            f32x4 c = {};
            c = __builtin_amdgcn_mfma_f32_16x16x32_bf16(aq0, b0, c, 0, 0, 0);
            c = __builtin_amdgcn_mfma_f32_16x16x32_bf16(aq1, b1, c, 0, 0, 0);
            s4[j] = c;
        }

        // online softmax; lane's rows are quad*4 + r
        for (int r = 0; r < 4; ++r) {
            float sv0 = s4[0][r] * scale, sv1 = s4[1][r] * scale;
            float sv2 = s4[2][r] * scale, sv3 = s4[3][r] * scale;
            float mt = fmaxf(fmaxf(sv0, sv1), fmaxf(sv2, sv3));
            for (int off = 1; off < 16; off <<= 1)
                mt = fmaxf(mt, __shfl_xor(mt, off, 64));
            float mn = fmaxf(m_i[r], mt);
            float alpha = __expf(m_i[r] - mn);
            m_i[r] = mn;
            float p0 = __expf(sv0 - mn), p1 = __expf(sv1 - mn);
            float p2 = __expf(sv2 - mn), p3 = __expf(sv3 - mn);
            u16* pw = Ps[wave] + (quad * 4 + r) * 64 + l15;
            pw[0]  = f2bf(p0);
            pw[16] = f2bf(p1);
            pw[32] = f2bf(p2);
            pw[48] = f2bf(p3);
            float rs = p0 + p1 + p2 + p3;
            for (int off = 1; off < 16; off <<= 1)
                rs += __shfl_xor(rs, off, 64);
            l_i[r] = l_i[r] * alpha + rs;
            for (int dt = 0; dt < 4; ++dt) o[dt][r] *= alpha;
        }

        // O += P @ V
        for (int kk = 0; kk < 64; kk += 32) {
            s16x8 pf = *(const s16x8*)(Ps[wave] + l15 * 64 + kk + quad * 8);
            for (int dt = 0; dt < 4; ++dt) {
                const u16* vr = Vts + (dt * 16 + l15) * 68 + kk + quad * 8;
                s16x4 v0 = *(const s16x4*)(vr);
                s16x4 v1 = *(const s16x4*)(vr + 4);
                s16x8 vf;
                vf[0] = v0[0]; vf[1] = v0[1]; vf[2] = v0[2]; vf[3] = v0[3];
                vf[4] = v1[0]; vf[5] = v1[1]; vf[6] = v1[2]; vf[7] = v1[3];
                o[dt] = __builtin_amdgcn_mfma_f32_16x16x32_bf16(pf, vf, o[dt], 0, 0, 0);
            }
        }
    }

    int b = bh >> 2, h = bh & 3;
    float rl[4];
    for (int r = 0; r < 4; ++r) rl[r] = 1.0f / l_i[r];
    for (int dt = 0; dt < 4; ++dt)
        for (int r = 0; r < 4; ++r) {
            int qrow = q0 + wave * 16 + quad * 4 + r;
            aout[((size_t)(b) * 1024 + qrow) * 256 + h * 64 + dt * 16 + l15] =
                f2bf(o[dt][r] * rl[r]);
        }
}

// ---------------------------------------------------------------------------
// GEMM2: y[8192][4096] = aout[8192][256] @ W_outT^T + bias, fused shuffle.
// ---------------------------------------------------------------------------
__global__ __launch_bounds__(256) void k_gemm_out(const u16* __restrict__ A,
                                                  const u16* __restrict__ Bt,
                                                  const float* __restrict__ bias,
                                                  float* __restrict__ out) {
    const int K = 256;
    __shared__ u16 As[128 * 64];
    __shared__ u16 Bs[128 * 64];
    const int tid = threadIdx.x;
    const int wave = tid >> 6, lane = tid & 63;
    const int quad = lane >> 4, l15 = lane & 15;
    const int wm = wave >> 1, wn = wave & 1;
    const int tm = blockIdx.y * 128, tn = blockIdx.x * 128;

    f32x4 acc[4][4] = {};

    for (int k0 = 0; k0 < K; k0 += 64) {
        __syncthreads();
        for (int t = 0; t < 4; ++t) {
            int c = wave * 256 + t * 64 + lane;
            int row = c >> 3, kc = c & 7;
            gl_lds16(A + (size_t)(tm + row) * K + k0 + kc * 8,
                     As + (wave * 256 + t * 64) * 8);
        }
        for (int t = 0; t < 4; ++t) {
            int c = wave * 256 + t * 64 + lane;
            int row = c >> 3, kc = c & 7;
            gl_lds16(Bt + (size_t)(tn + row) * K + k0 + kc * 8,
                     Bs + (wave * 256 + t * 64) * 8);
        }
        __syncthreads();
        for (int kk = 0; kk < 64; kk += 32) {
            s16x8 af[4], bf[4];
            for (int i = 0; i < 4; ++i)
                af[i] = *(const s16x8*)(As + (wm * 64 + i * 16 + l15) * 64 + kk + quad * 8);
            for (int j = 0; j < 4; ++j)
                bf[j] = *(const s16x8*)(Bs + (wn * 64 + j * 16 + l15) * 64 + kk + quad * 8);
            for (int i = 0; i < 4; ++i)
                for (int j = 0; j < 4; ++j)
                    acc[i][j] = __builtin_amdgcn_mfma_f32_16x16x32_bf16(af[i], bf[j], acc[i][j], 0, 0, 0);
        }
    }

    for (int i = 0; i < 4; ++i) {
        int mb = tm + wm * 64 + i * 16 + quad * 4;
        for (int j = 0; j < 4; ++j) {
            int col = tn + wn * 64 + j * 16 + l15;
            float bb = bias[col];
            int c0 = col >> 6, r1 = (col >> 3) & 7, r2 = col & 7;
            for (int r = 0; r < 4; ++r) {
                int m = mb + r;
                int b = m >> 10, n = m & 1023, yy = n >> 5, xx = n & 31;
                size_t oidx = ((size_t)((b * 64 + c0) * 256 + yy * 8 + r1)) * 256 + xx * 8 + r2;
                out[oidx] = acc[i][j][r] + bb;
            }
        }
    }
}

// ---------------------------------------------------------------------------
extern "C" void kernel_launch(void* const* d_in, const int* in_sizes, int n_in,
                              void* d_out, int out_size, void* d_ws, size_t ws_size,
                              hipStream_t stream) {
    (void)in_sizes; (void)n_in; (void)out_size; (void)ws_size;
    const float* x    = (const float*)d_in[0];
    const float* Wqkv = (const float*)d_in[1];   // [4096][768]
    const float* Wout = (const float*)d_in[2];   // [256][4096]
    const float* bout = (const float*)d_in[3];   // [4096]
    float* out = (float*)d_out;

    u16* ws     = (u16*)d_ws;
    u16* wqkvT  = ws;                        // 768*4096 (pre-swizzled)
    u16* woutT  = wqkvT + 3145728;           // 4096*256
    u16* Qb     = woutT + 1048576;           // 32*1024*64
    u16* Kb     = Qb + 2097152;
    u16* Vtb    = Kb + 2097152;              // V transposed [bh][d][n]
    u16* aoutb  = Vtb + 2097152;             // 8192*256
    float* Pp   = (float*)(aoutb + 2097152); // 4*8192*768 f32

    k_transpose<<<dim3(12, 64), 256, 0, stream>>>(Wqkv, wqkvT, 4096, 768, 1);
    k_transpose<<<dim3(64, 4), 256, 0, stream>>>(Wout, woutT, 256, 4096, 0);
    k_gemm_qkv<<<dim3(384, 1, 1), 512, 0, stream>>>(x, wqkvT, Pp);
    k_qkv_reduce<<<dim3(12, 128), 256, 0, stream>>>(Pp, Qb, Kb, Vtb);
    k_attn<<<dim3(16, 32), 256, 0, stream>>>(Qb, Kb, Vtb, aoutb);
    k_gemm_out<<<dim3(32, 64), 256, 0, stream>>>(aoutb, woutT, bout, out);
}